// Round 13
// baseline (759.109 us; speedup 1.0000x reference)
//
#include <hip/hip_runtime.h>
#include <cstdint>
#include <cstddef>

// ---------------------------------------------------------------------------
// RNN_No_FFNN: h_t = sigmoid(hidden@U_w.T + U_b + line@W_w.T + W_b)
//              pred = h_t@V_w.T + V_b ; out0 = segmented log_softmax(pred)
// B=8192, H=2048, D=104.  Outputs: [pred_logsoft (8192*104) | h_t (8192*2048)] f32.
// gemm1 (R13): MX-fp8 e4m3 (unit scales), 128x128 tile, BK=64 (34 K-tiles),
//   512 thr / 8 waves (2x4, 64x32 out each), 2x16KB LDS bufs (32KB)
//   -> launch_bounds(512,8) -> 4 blocks/CU = 32 waves/CU (occupancy lever,
//   R11->R12 measured +13us for 8->16 waves). Plane layout (0 conflicts,
//   R11/R12-measured). 2 GLDs/K-tile/thread, vmcnt(2) gate -> barrier -> read.
// gemm2: REVERT to R8's 64-row/128-block version (R12's 32-row doubled
//   B-staging traffic and regressed the total).
// ---------------------------------------------------------------------------

typedef __bf16 bf16x8 __attribute__((ext_vector_type(8)));
typedef float  f32x4  __attribute__((ext_vector_type(4)));
typedef float  f32x16 __attribute__((ext_vector_type(16)));
typedef int    i32x4  __attribute__((ext_vector_type(4)));
typedef int    i32x8  __attribute__((ext_vector_type(8)));
typedef unsigned short ushort8 __attribute__((ext_vector_type(8)));
typedef unsigned char  uchar8  __attribute__((ext_vector_type(8)));
typedef float  float4v __attribute__((ext_vector_type(4)));

#define BB 8192
#define HH 2048
#define DD 104

static __device__ __forceinline__ unsigned short f2bf(float f) {
  unsigned u = __float_as_uint(f);
  unsigned r = (u + 0x7FFFu + ((u >> 16) & 1u)) >> 16;  // RNE
  return (unsigned short)r;
}

// f32 -> OCP e4m3fn, RNE, saturate to 448. Subnormal grid 2^-9.
static __device__ __forceinline__ unsigned char f2fp8(float x) {
  unsigned u = __float_as_uint(x);
  unsigned s = (u >> 24) & 0x80u;
  float ax = fabsf(x);
  ax = fminf(ax, 448.0f);
  unsigned code;
  if (ax >= 0.015625f) {                    // normal: exp >= -6
    unsigned b = __float_as_uint(ax);
    unsigned lsb = (b >> 20) & 1u;
    b += 0x0007FFFFu + lsb;                 // RNE at mantissa bit 20
    unsigned e = (b >> 23) & 0xFFu;
    code = ((e - 120u) << 3) | ((b >> 20) & 7u);
  } else {
    code = (unsigned)__float2int_rn(ax * 512.0f);
  }
  return (unsigned char)(s | code);
}

// async global->LDS, 16B per lane (dest = wave-uniform base + lane*16: linear)
#define GLD_LDS(g, l)                                                          \
  __builtin_amdgcn_global_load_lds(                                            \
      (__attribute__((address_space(1))) void*)(g),                            \
      (__attribute__((address_space(3))) void*)(l), 16, 0, 0)

#define MEMFENCE asm volatile("" ::: "memory")
#define MFMA16(a, b, c) __builtin_amdgcn_mfma_f32_16x16x32_bf16((a), (b), (c), 0, 0, 0)

// ---------------------------------------------------------------------------
// Conversion kernels (unchanged)
// ---------------------------------------------------------------------------
__global__ __launch_bounds__(256) void conv_fp8_kernel(
    const float* __restrict__ hidden, const float* __restrict__ Uw,
    unsigned char* __restrict__ out_h, unsigned char* __restrict__ out_u) {
  long long i = ((long long)blockIdx.x * blockDim.x + threadIdx.x) * 8;
  const float* src; unsigned char* dst; long long off;
  if (i < (long long)BB * HH) { src = hidden; dst = out_h; off = i; }
  else { src = Uw; dst = out_u; off = i - (long long)BB * HH; }
  float4v a = *(const float4v*)(src + off);
  float4v b = *(const float4v*)(src + off + 4);
  uchar8 o;
  o[0]=f2fp8(a[0]); o[1]=f2fp8(a[1]); o[2]=f2fp8(a[2]); o[3]=f2fp8(a[3]);
  o[4]=f2fp8(b[0]); o[5]=f2fp8(b[1]); o[6]=f2fp8(b[2]); o[7]=f2fp8(b[3]);
  *(uchar8*)(dst + off) = o;
}

__global__ __launch_bounds__(256) void pad_mixed_kernel(
    const float* __restrict__ line, const float* __restrict__ Ww,
    const float* __restrict__ Vw,
    unsigned char* __restrict__ line8, unsigned char* __restrict__ Ww8,
    unsigned short* __restrict__ Vw_bf) {
  int i = blockIdx.x * blockDim.x + threadIdx.x;
  const int N1 = BB * 128;          // 1048576
  const int N2 = N1 + HH * 128;     // 1310720
  if (i < N1) {
    int r = i >> 7, c = i & 127;
    line8[i] = (c < DD) ? f2fp8(line[r * DD + c]) : (unsigned char)0;
  } else if (i < N2) {
    int j = i - N1; int r = j >> 7, c = j & 127;
    Ww8[j] = (c < DD) ? f2fp8(Ww[r * DD + c]) : (unsigned char)0;
  } else {
    int j = i - N2; int r = j >> 11, c = j & 2047;
    Vw_bf[j] = (r < DD) ? f2bf(Vw[r * 2048 + c]) : (unsigned short)0;
  }
}

// ---------------------------------------------------------------------------
// GEMM1 (R13).
// LDS: A bufs [0,16384) (buf b at b*8192), B bufs [16384,32768).
// Per buf 8KB = [plane:4][row:128][16B]; plane p holds k [kb+p*16, +16).
// Staging (2 GLDs/K-tile/thread, 512 thr): thread t: row = t&127,
//   plane = t>>7 (0..3); src = row*stride + kb + (t>>7)*16;
//   dest = buf*8192 + t*16  (t*16 = (t>>7)*2048 + (t&127)*16 = plane-major ✓).
// Fragment (lane lr=l&31, lc=l>>5): 32B = planes {2lc, 2lc+1}: two b128 at
//   (2lc)*2048 + row*16 (+2048). Bank-base (row*4)&31 -> free (measured 0).
// Same (lane,byte)->k bijection for A and B -> dot exact (R7-R12 validated).
// Waves 2x4: wr=wid>>2 (64-row band), wc=wid&3 (32-col band). acc[2].
// ---------------------------------------------------------------------------
static __device__ __forceinline__ i32x8 frd(const unsigned char* buf, int row, int pbase) {
  const unsigned char* p = buf + pbase * 2048 + row * 16;
  i32x4 lo = *(const i32x4*)(p);
  i32x4 hi = *(const i32x4*)(p + 2048);
  i32x8 r;
  r[0]=lo[0]; r[1]=lo[1]; r[2]=lo[2]; r[3]=lo[3];
  r[4]=hi[0]; r[5]=hi[1]; r[6]=hi[2]; r[7]=hi[3];
  return r;
}

__global__ __launch_bounds__(512, 8) void gemm1_kernel(
    const unsigned char* __restrict__ A8,   // hidden fp8 [8192][2048]
    const unsigned char* __restrict__ L8,   // line fp8 [8192][128] (zero-pad)
    const unsigned char* __restrict__ U8w,  // U_w fp8 [2048][2048]
    const unsigned char* __restrict__ W8w,  // W_w fp8 [2048][128] (zero-pad)
    const float* __restrict__ Ub, const float* __restrict__ Wb,
    float* __restrict__ outH, unsigned short* __restrict__ outHbf) {
  __shared__ __attribute__((aligned(16))) unsigned char smem[32768];  // 32 KB
  const int t = threadIdx.x;
  const int l = t & 63;
  const int wid = t >> 6;
  const int wr = wid >> 2, wc = wid & 3;    // 2 x 4 waves, 64x32 out each

  // bijective XCD-chunked swizzle: 1024 wgs, 8 XCDs, 128/chunk
  const int bid = blockIdx.x;
  const int wg = (bid & 7) * 128 + (bid >> 3);
  const int brow = (wg >> 4) * 128;   // 64 M tiles
  const int bcol = (wg & 15) * 128;   // 16 N tiles

  const int lr = l & 31;              // fragment row within 32-row band
  const int lc = l >> 5;              // k-half select

  // staging addressing: row = t&127, plane = t>>7
  const int sr = t & 127;
  const int sp = (t >> 7) * 16;
  const unsigned char* pA = A8 + (size_t)(brow + sr) * 2048 + sp;
  const unsigned char* pL = L8 + (size_t)(brow + sr) * 128 + sp;
  const unsigned char* pU = U8w + (size_t)(bcol + sr) * 2048 + sp;
  const unsigned char* pW = W8w + (size_t)(bcol + sr) * 128 + sp;
  unsigned char* dA = smem + t * 16;            // + buf*8192
  unsigned char* dB = smem + 16384 + t * 16;

  f32x16 acc[2] = {};   // m in {0,1}; single n band per wave

  auto stage = [&](int kt, int buf) {
    const int kb = kt * 64;
    if (kb < 2048) {
      GLD_LDS(pA + kb, dA + buf * 8192);
      GLD_LDS(pU + kb, dB + buf * 8192);
    } else {  // K-tail: line/W_w pads (kb2 = 0 or 64)
      const int kb2 = kb - 2048;
      GLD_LDS(pL + kb2, dA + buf * 8192);
      GLD_LDS(pW + kb2, dB + buf * 8192);
    }
  };

  // prologue
  stage(0, 0);
  // K = 2176 = 34 tiles of 64 (32 from hidden/U_w, 2 pad tiles)
  for (int kt = 0; kt < 34; ++kt) {
    const int cur = kt & 1;
    if (kt < 33) {
      stage(kt + 1, cur ^ 1);
      asm volatile("s_waitcnt vmcnt(2)" ::: "memory");  // my tile-kt GLDs landed
    } else {
      asm volatile("s_waitcnt vmcnt(0)" ::: "memory");
    }
    MEMFENCE; __builtin_amdgcn_s_barrier(); MEMFENCE;   // ALL waves' kt landed

    const unsigned char* Ab = smem + cur * 8192;
    const unsigned char* Bb = smem + 16384 + cur * 8192;
    const int pb = lc * 2;
    i32x8 af0 = frd(Ab, wr * 64 + lr, pb);
    i32x8 af1 = frd(Ab, wr * 64 + 32 + lr, pb);
    i32x8 bf_ = frd(Bb, wc * 32 + lr, pb);
    __builtin_amdgcn_s_setprio(1);
    acc[0] = __builtin_amdgcn_mfma_scale_f32_32x32x64_f8f6f4(
        af0, bf_, acc[0], 0, 0, 0, 0x7F7F7F7F, 0, 0x7F7F7F7F);
    acc[1] = __builtin_amdgcn_mfma_scale_f32_32x32x64_f8f6f4(
        af1, bf_, acc[1], 0, 0, 0, 0x7F7F7F7F, 0, 0x7F7F7F7F);
    __builtin_amdgcn_s_setprio(0);
    MEMFENCE; __builtin_amdgcn_s_barrier(); MEMFENCE;   // reads done -> buf reusable
  }

  // epilogue: +bias, sigmoid, dual write.
  // C/D 32x32: n = l&31, m = (reg&3) + 8*(reg>>2) + 4*(l>>5)
  {
    const int col = bcol + wc * 32 + lr;
    const float bias = Ub[col] + Wb[col];
#pragma unroll
    for (int mf = 0; mf < 2; ++mf) {
#pragma unroll
      for (int reg = 0; reg < 16; ++reg) {
        const int row = brow + wr * 64 + mf * 32 + (reg & 3) + 8 * (reg >> 2) + 4 * lc;
        const float v = acc[mf][reg] + bias;
        const float h = 1.0f / (1.0f + __expf(-v));
        const size_t idx = (size_t)row * HH + col;
        outH[idx] = h;
        outHbf[idx] = f2bf(h);
      }
    }
  }
}

// ---------------------------------------------------------------------------
// GEMM2 (revert to R8): 64-row tiles, 128 blocks. pred = h_t@V_w.T + V_b +
// fused segmented log-softmax. Waves 2x2: 32 rows x 64 cols each, acc[2][4].
// ---------------------------------------------------------------------------
template <int NM, int NN>
static __device__ __forceinline__ void mfma_step(
    const unsigned short* sA, const unsigned short* sB, int arow0, int brow0,
    int frow, int fk, f32x4 (&acc)[NM][NN]) {
  bf16x8 af[NM], bfr[NN];
#pragma unroll
  for (int m = 0; m < NM; ++m)
    af[m] = *(const bf16x8*)(sA + (arow0 + m * 16 + frow) * 32 + fk);
#pragma unroll
  for (int n = 0; n < NN; ++n)
    bfr[n] = *(const bf16x8*)(sB + (brow0 + n * 16 + frow) * 32 + fk);
#pragma unroll
  for (int m = 0; m < NM; ++m)
#pragma unroll
    for (int n = 0; n < NN; ++n)
      acc[m][n] = MFMA16(af[m], bfr[n], acc[m][n]);
}

__global__ __launch_bounds__(256, 2) void gemm2_kernel(
    const unsigned short* __restrict__ A,   // h_t bf16 [8192][2048]
    const unsigned short* __restrict__ Bm,  // Vw_bf [128][2048]
    const float* __restrict__ Vb,
    float* __restrict__ outLS) {            // [8192][104] f32
  __shared__ unsigned short sA[64 * 32];
  __shared__ unsigned short sB[128 * 32];
  __shared__ float pred[64 * 105];
  const int t = threadIdx.x;
  const int l = t & 63;
  const int wid = t >> 6, wr = wid >> 1, wc = wid & 1;
  const int brow = blockIdx.x * 64;
  const int srow = t >> 2, scg = t & 3;
  const int frow = l & 15, fk = (l >> 4) * 8;

  const unsigned short* gA = A + (size_t)(brow + srow) * HH + scg * 8;
  const unsigned short* gB = Bm + (size_t)srow * HH + scg * 8;
  unsigned short* lA = sA + t * 8;
  unsigned short* lB = sB + t * 8;

  f32x4 acc[2][4] = {};
  for (int ks = 0; ks < 64; ++ks) {
    __syncthreads();
    GLD_LDS(gA, lA);
    GLD_LDS(gB, lB);
    GLD_LDS(gB + 64 * HH, lB + 64 * 32);
    gA += 32; gB += 32;
    __syncthreads();
    mfma_step<2, 4>(sA, sB, wr * 32, wc * 64, frow, fk, acc);
  }

#pragma unroll
  for (int n = 0; n < 4; ++n) {
    const int col = wc * 64 + n * 16 + frow;
    if (col < DD) {
      const float vb = Vb[col];
#pragma unroll
      for (int m = 0; m < 2; ++m) {
        const int r0 = wr * 32 + m * 16 + (l >> 4) * 4;
#pragma unroll
        for (int j = 0; j < 4; ++j)
          pred[(r0 + j) * 105 + col] = acc[m][n][j] + vb;
      }
    }
  }
  __syncthreads();

  if (t < 64) {
    const int segb[11] = {0, 13, 26, 39, 48, 52, 65, 78, 91, 100, 104};
    const float* p = pred + t * 105;
    float* o = outLS + (size_t)(brow + t) * DD;
    for (int s = 0; s < 10; ++s) {
      const int a = segb[s], b = segb[s + 1];
      float mx = -3.0e38f;
      for (int c = a; c < b; ++c) mx = fmaxf(mx, p[c]);
      float sum = 0.0f;
      for (int c = a; c < b; ++c) sum += __expf(p[c] - mx);
      const float ls = __logf(sum) + mx;
      for (int c = a; c < b; ++c) o[c] = p[c] - ls;
    }
  }
}

// ---------------------------------------------------------------------------
// Launch
// ---------------------------------------------------------------------------
extern "C" void kernel_launch(void* const* d_in, const int* in_sizes, int n_in,
                              void* d_out, int out_size, void* d_ws, size_t ws_size,
                              hipStream_t stream) {
  (void)in_sizes; (void)n_in; (void)out_size; (void)ws_size;
  const float* line   = (const float*)d_in[0];
  const float* hidden = (const float*)d_in[1];
  const float* Uw     = (const float*)d_in[2];
  const float* Ub     = (const float*)d_in[3];
  const float* Ww     = (const float*)d_in[4];
  const float* Wb     = (const float*)d_in[5];
  const float* Vw     = (const float*)d_in[6];
  const float* Vb     = (const float*)d_in[7];

  char* ws = (char*)d_ws;
  unsigned char* hid8    = (unsigned char*)(ws);               // 16,777,216
  unsigned char* U8w     = (unsigned char*)(ws + 16777216);    //  4,194,304
  unsigned char* line8   = (unsigned char*)(ws + 20971520);    //  1,048,576
  unsigned char* Ww8     = (unsigned char*)(ws + 22020096);    //    262,144
  unsigned short* Vw_bf  = (unsigned short*)(ws + 22282240);   //    524,288
  unsigned short* ht_bf  = (unsigned short*)(ws + 22806528);   // 33,554,432

  float* outLS = (float*)d_out;                    // [8192][104]
  float* outH  = (float*)d_out + (size_t)BB * DD;  // [8192][2048]

  conv_fp8_kernel<<<10240, 256, 0, stream>>>(hidden, Uw, hid8, U8w);
  pad_mixed_kernel<<<6144, 256, 0, stream>>>(line, Ww, Vw, line8, Ww8, Vw_bf);
  gemm1_kernel<<<1024, 512, 0, stream>>>(hid8, line8, U8w, Ww8, Ub, Wb,
                                         outH, ht_bf);
  gemm2_kernel<<<128, 256, 0, stream>>>(ht_bf, Vw_bf, Vb, outLS);
}

// Round 14
// 140.234 us; speedup vs baseline: 5.4131x; 5.4131x over previous
//
#include <hip/hip_runtime.h>
#include <cstdint>
#include <cstddef>

// ---------------------------------------------------------------------------
// RNN_No_FFNN: h_t = sigmoid(hidden@U_w.T + U_b + line@W_w.T + W_b)
//              pred = h_t@V_w.T + V_b ; out0 = segmented log_softmax(pred)
// B=8192, H=2048, D=104.  Outputs: [pred_logsoft (8192*104) | h_t (8192*2048)] f32.
// R14 = best measured combination:
//  gemm1 = R12 exact (91us): MX-fp8, 128x128 tile, BK=128, 512thr/8 waves,
//    launch_bounds(512,4) [R13's (512,8) starved VGPR->scratch spill, 7x slower],
//    64KB LDS dbuf, plane layout (0 conflicts), vmcnt(4) gate.
//  gemm2 = R8 exact (64-row/128-block; R12's 32-row doubled B traffic).
// ---------------------------------------------------------------------------

typedef __bf16 bf16x8 __attribute__((ext_vector_type(8)));
typedef float  f32x4  __attribute__((ext_vector_type(4)));
typedef float  f32x16 __attribute__((ext_vector_type(16)));
typedef int    i32x4  __attribute__((ext_vector_type(4)));
typedef int    i32x8  __attribute__((ext_vector_type(8)));
typedef unsigned short ushort8 __attribute__((ext_vector_type(8)));
typedef unsigned char  uchar8  __attribute__((ext_vector_type(8)));
typedef float  float4v __attribute__((ext_vector_type(4)));

#define BB 8192
#define HH 2048
#define DD 104

static __device__ __forceinline__ unsigned short f2bf(float f) {
  unsigned u = __float_as_uint(f);
  unsigned r = (u + 0x7FFFu + ((u >> 16) & 1u)) >> 16;  // RNE
  return (unsigned short)r;
}

// f32 -> OCP e4m3fn, RNE, saturate to 448. Subnormal grid 2^-9.
static __device__ __forceinline__ unsigned char f2fp8(float x) {
  unsigned u = __float_as_uint(x);
  unsigned s = (u >> 24) & 0x80u;
  float ax = fabsf(x);
  ax = fminf(ax, 448.0f);
  unsigned code;
  if (ax >= 0.015625f) {                    // normal: exp >= -6
    unsigned b = __float_as_uint(ax);
    unsigned lsb = (b >> 20) & 1u;
    b += 0x0007FFFFu + lsb;                 // RNE at mantissa bit 20
    unsigned e = (b >> 23) & 0xFFu;
    code = ((e - 120u) << 3) | ((b >> 20) & 7u);
  } else {
    code = (unsigned)__float2int_rn(ax * 512.0f);
  }
  return (unsigned char)(s | code);
}

// async global->LDS, 16B per lane (dest = wave-uniform base + lane*16: linear)
#define GLD_LDS(g, l)                                                          \
  __builtin_amdgcn_global_load_lds(                                            \
      (__attribute__((address_space(1))) void*)(g),                            \
      (__attribute__((address_space(3))) void*)(l), 16, 0, 0)

#define MEMFENCE asm volatile("" ::: "memory")
#define MFMA16(a, b, c) __builtin_amdgcn_mfma_f32_16x16x32_bf16((a), (b), (c), 0, 0, 0)

// ---------------------------------------------------------------------------
// Conversion kernels (unchanged)
// ---------------------------------------------------------------------------
__global__ __launch_bounds__(256) void conv_fp8_kernel(
    const float* __restrict__ hidden, const float* __restrict__ Uw,
    unsigned char* __restrict__ out_h, unsigned char* __restrict__ out_u) {
  long long i = ((long long)blockIdx.x * blockDim.x + threadIdx.x) * 8;
  const float* src; unsigned char* dst; long long off;
  if (i < (long long)BB * HH) { src = hidden; dst = out_h; off = i; }
  else { src = Uw; dst = out_u; off = i - (long long)BB * HH; }
  float4v a = *(const float4v*)(src + off);
  float4v b = *(const float4v*)(src + off + 4);
  uchar8 o;
  o[0]=f2fp8(a[0]); o[1]=f2fp8(a[1]); o[2]=f2fp8(a[2]); o[3]=f2fp8(a[3]);
  o[4]=f2fp8(b[0]); o[5]=f2fp8(b[1]); o[6]=f2fp8(b[2]); o[7]=f2fp8(b[3]);
  *(uchar8*)(dst + off) = o;
}

__global__ __launch_bounds__(256) void pad_mixed_kernel(
    const float* __restrict__ line, const float* __restrict__ Ww,
    const float* __restrict__ Vw,
    unsigned char* __restrict__ line8, unsigned char* __restrict__ Ww8,
    unsigned short* __restrict__ Vw_bf) {
  int i = blockIdx.x * blockDim.x + threadIdx.x;
  const int N1 = BB * 128;          // 1048576
  const int N2 = N1 + HH * 128;     // 1310720
  if (i < N1) {
    int r = i >> 7, c = i & 127;
    line8[i] = (c < DD) ? f2fp8(line[r * DD + c]) : (unsigned char)0;
  } else if (i < N2) {
    int j = i - N1; int r = j >> 7, c = j & 127;
    Ww8[j] = (c < DD) ? f2fp8(Ww[r * DD + c]) : (unsigned char)0;
  } else {
    int j = i - N2; int r = j >> 11, c = j & 2047;
    Vw_bf[j] = (r < DD) ? f2bf(Vw[r * 2048 + c]) : (unsigned short)0;
  }
}

// ---------------------------------------------------------------------------
// GEMM1 (R12 exact, 91us best).
// LDS: A bufs [0,32768) (buf b at b*16384), B bufs [32768,65536).
// Per buf 16KB = [plane:8][row:128][16B]; plane p holds k [kb+p*16, +16).
// Staging (4 GLDs/K-tile/thread, 512 thr): thread t: row sr = t&127,
//   plane-in-half sp4 = t>>7 (0..3). GLD q (0,1): src = row*stride + kb +
//   q*64 + sp4*16 -> plane q*4+sp4; dest = buf*16384 + q*8192 + t*16 (linear).
// Fragment (MFMA step s, lane lr=l&31, lc=l>>5): 32B = planes {s*4+lc*2,+1}:
//   two b128 at pbase*2048 + row*16 (+2048). 0 conflicts (measured).
// Same (lane,byte)->k bijection for A and B -> dot exact (R7-R12 validated).
// Waves 2x4: wr=wid>>2 (64-row band), wc=wid&3 (32-col band). acc[2].
// ---------------------------------------------------------------------------
static __device__ __forceinline__ i32x8 frd(const unsigned char* buf, int row, int pbase) {
  const unsigned char* p = buf + pbase * 2048 + row * 16;
  i32x4 lo = *(const i32x4*)(p);
  i32x4 hi = *(const i32x4*)(p + 2048);
  i32x8 r;
  r[0]=lo[0]; r[1]=lo[1]; r[2]=lo[2]; r[3]=lo[3];
  r[4]=hi[0]; r[5]=hi[1]; r[6]=hi[2]; r[7]=hi[3];
  return r;
}

__global__ __launch_bounds__(512, 4) void gemm1_kernel(
    const unsigned char* __restrict__ A8,   // hidden fp8 [8192][2048]
    const unsigned char* __restrict__ L8,   // line fp8 [8192][128] (zero-pad)
    const unsigned char* __restrict__ U8w,  // U_w fp8 [2048][2048]
    const unsigned char* __restrict__ W8w,  // W_w fp8 [2048][128] (zero-pad)
    const float* __restrict__ Ub, const float* __restrict__ Wb,
    float* __restrict__ outH, unsigned short* __restrict__ outHbf) {
  __shared__ __attribute__((aligned(16))) unsigned char smem[65536];  // 64 KB
  const int t = threadIdx.x;
  const int l = t & 63;
  const int wid = t >> 6;
  const int wr = wid >> 2, wc = wid & 3;    // 2 x 4 waves, 64x32 out each

  // bijective XCD-chunked swizzle: 1024 wgs, 8 XCDs, 128/chunk
  const int bid = blockIdx.x;
  const int wg = (bid & 7) * 128 + (bid >> 3);
  const int brow = (wg >> 4) * 128;   // 64 M tiles
  const int bcol = (wg & 15) * 128;   // 16 N tiles

  const int lr = l & 31;              // fragment row within 32-row band
  const int lc = l >> 5;              // k-half select

  // staging addressing: row = t&127, plane-in-half = t>>7
  const int sr = t & 127;
  const int sp = (t >> 7) * 16;
  const unsigned char* pA = A8 + (size_t)(brow + sr) * 2048 + sp;
  const unsigned char* pL = L8 + (size_t)(brow + sr) * 128 + sp;
  const unsigned char* pU = U8w + (size_t)(bcol + sr) * 2048 + sp;
  const unsigned char* pW = W8w + (size_t)(bcol + sr) * 128 + sp;
  unsigned char* dA = smem + t * 16;            // + buf*16384 + q*8192
  unsigned char* dB = smem + 32768 + t * 16;

  f32x16 acc[2] = {};   // m in {0,1}; single n band per wave

  auto stage = [&](int kt, int buf) {
    unsigned char* da = dA + buf * 16384;
    unsigned char* db = dB + buf * 16384;
    const int kb = kt * 128;
    if (kb < 2048) {
#pragma unroll
      for (int q = 0; q < 2; ++q) {
        GLD_LDS(pA + kb + q * 64, da + q * 8192);
        GLD_LDS(pU + kb + q * 64, db + q * 8192);
      }
    } else {  // K-tail: line/W_w pads (exactly one 128-wide K-tile)
#pragma unroll
      for (int q = 0; q < 2; ++q) {
        GLD_LDS(pL + q * 64, da + q * 8192);
        GLD_LDS(pW + q * 64, db + q * 8192);
      }
    }
  };

  // prologue
  stage(0, 0);
  // K = 2176 = 17 tiles of 128 (16 from hidden/U_w, 1 pad tile)
  for (int kt = 0; kt < 17; ++kt) {
    const int cur = kt & 1;
    if (kt < 16) {
      stage(kt + 1, cur ^ 1);
      asm volatile("s_waitcnt vmcnt(4)" ::: "memory");  // my tile-kt GLDs landed
    } else {
      asm volatile("s_waitcnt vmcnt(0)" ::: "memory");
    }
    MEMFENCE; __builtin_amdgcn_s_barrier(); MEMFENCE;   // ALL waves' kt landed

    const unsigned char* Ab = smem + cur * 16384;
    const unsigned char* Bb = smem + 32768 + cur * 16384;
#pragma unroll
    for (int s = 0; s < 2; ++s) {           // two K=64 MFMA steps
      const int pb = s * 4 + lc * 2;
      i32x8 af0 = frd(Ab, wr * 64 + lr, pb);
      i32x8 af1 = frd(Ab, wr * 64 + 32 + lr, pb);
      i32x8 bf_ = frd(Bb, wc * 32 + lr, pb);
      __builtin_amdgcn_s_setprio(1);
      acc[0] = __builtin_amdgcn_mfma_scale_f32_32x32x64_f8f6f4(
          af0, bf_, acc[0], 0, 0, 0, 0x7F7F7F7F, 0, 0x7F7F7F7F);
      acc[1] = __builtin_amdgcn_mfma_scale_f32_32x32x64_f8f6f4(
          af1, bf_, acc[1], 0, 0, 0, 0x7F7F7F7F, 0, 0x7F7F7F7F);
      __builtin_amdgcn_s_setprio(0);
    }
    MEMFENCE; __builtin_amdgcn_s_barrier(); MEMFENCE;   // reads done -> buf reusable
  }

  // epilogue: +bias, sigmoid, dual write.
  // C/D 32x32: n = l&31, m = (reg&3) + 8*(reg>>2) + 4*(l>>5)
  {
    const int col = bcol + wc * 32 + lr;
    const float bias = Ub[col] + Wb[col];
#pragma unroll
    for (int mf = 0; mf < 2; ++mf) {
#pragma unroll
      for (int reg = 0; reg < 16; ++reg) {
        const int row = brow + wr * 64 + mf * 32 + (reg & 3) + 8 * (reg >> 2) + 4 * lc;
        const float v = acc[mf][reg] + bias;
        const float h = 1.0f / (1.0f + __expf(-v));
        const size_t idx = (size_t)row * HH + col;
        outH[idx] = h;
        outHbf[idx] = f2bf(h);
      }
    }
  }
}

// ---------------------------------------------------------------------------
// GEMM2 (R8 exact): 64-row tiles, 128 blocks. pred = h_t@V_w.T + V_b +
// fused segmented log-softmax. Waves 2x2: 32 rows x 64 cols each, acc[2][4].
// ---------------------------------------------------------------------------
template <int NM, int NN>
static __device__ __forceinline__ void mfma_step(
    const unsigned short* sA, const unsigned short* sB, int arow0, int brow0,
    int frow, int fk, f32x4 (&acc)[NM][NN]) {
  bf16x8 af[NM], bfr[NN];
#pragma unroll
  for (int m = 0; m < NM; ++m)
    af[m] = *(const bf16x8*)(sA + (arow0 + m * 16 + frow) * 32 + fk);
#pragma unroll
  for (int n = 0; n < NN; ++n)
    bfr[n] = *(const bf16x8*)(sB + (brow0 + n * 16 + frow) * 32 + fk);
#pragma unroll
  for (int m = 0; m < NM; ++m)
#pragma unroll
    for (int n = 0; n < NN; ++n)
      acc[m][n] = MFMA16(af[m], bfr[n], acc[m][n]);
}

__global__ __launch_bounds__(256, 2) void gemm2_kernel(
    const unsigned short* __restrict__ A,   // h_t bf16 [8192][2048]
    const unsigned short* __restrict__ Bm,  // Vw_bf [128][2048]
    const float* __restrict__ Vb,
    float* __restrict__ outLS) {            // [8192][104] f32
  __shared__ unsigned short sA[64 * 32];
  __shared__ unsigned short sB[128 * 32];
  __shared__ float pred[64 * 105];
  const int t = threadIdx.x;
  const int l = t & 63;
  const int wid = t >> 6, wr = wid >> 1, wc = wid & 1;
  const int brow = blockIdx.x * 64;
  const int srow = t >> 2, scg = t & 3;
  const int frow = l & 15, fk = (l >> 4) * 8;

  const unsigned short* gA = A + (size_t)(brow + srow) * HH + scg * 8;
  const unsigned short* gB = Bm + (size_t)srow * HH + scg * 8;
  unsigned short* lA = sA + t * 8;
  unsigned short* lB = sB + t * 8;

  f32x4 acc[2][4] = {};
  for (int ks = 0; ks < 64; ++ks) {
    __syncthreads();
    GLD_LDS(gA, lA);
    GLD_LDS(gB, lB);
    GLD_LDS(gB + 64 * HH, lB + 64 * 32);
    gA += 32; gB += 32;
    __syncthreads();
    mfma_step<2, 4>(sA, sB, wr * 32, wc * 64, frow, fk, acc);
  }

#pragma unroll
  for (int n = 0; n < 4; ++n) {
    const int col = wc * 64 + n * 16 + frow;
    if (col < DD) {
      const float vb = Vb[col];
#pragma unroll
      for (int m = 0; m < 2; ++m) {
        const int r0 = wr * 32 + m * 16 + (l >> 4) * 4;
#pragma unroll
        for (int j = 0; j < 4; ++j)
          pred[(r0 + j) * 105 + col] = acc[m][n][j] + vb;
      }
    }
  }
  __syncthreads();

  if (t < 64) {
    const int segb[11] = {0, 13, 26, 39, 48, 52, 65, 78, 91, 100, 104};
    const float* p = pred + t * 105;
    float* o = outLS + (size_t)(brow + t) * DD;
    for (int s = 0; s < 10; ++s) {
      const int a = segb[s], b = segb[s + 1];
      float mx = -3.0e38f;
      for (int c = a; c < b; ++c) mx = fmaxf(mx, p[c]);
      float sum = 0.0f;
      for (int c = a; c < b; ++c) sum += __expf(p[c] - mx);
      const float ls = __logf(sum) + mx;
      for (int c = a; c < b; ++c) o[c] = p[c] - ls;
    }
  }
}

// ---------------------------------------------------------------------------
// Launch
// ---------------------------------------------------------------------------
extern "C" void kernel_launch(void* const* d_in, const int* in_sizes, int n_in,
                              void* d_out, int out_size, void* d_ws, size_t ws_size,
                              hipStream_t stream) {
  (void)in_sizes; (void)n_in; (void)out_size; (void)ws_size;
  const float* line   = (const float*)d_in[0];
  const float* hidden = (const float*)d_in[1];
  const float* Uw     = (const float*)d_in[2];
  const float* Ub     = (const float*)d_in[3];
  const float* Ww     = (const float*)d_in[4];
  const float* Wb     = (const float*)d_in[5];
  const float* Vw     = (const float*)d_in[6];
  const float* Vb     = (const float*)d_in[7];

  char* ws = (char*)d_ws;
  unsigned char* hid8    = (unsigned char*)(ws);               // 16,777,216
  unsigned char* U8w     = (unsigned char*)(ws + 16777216);    //  4,194,304
  unsigned char* line8   = (unsigned char*)(ws + 20971520);    //  1,048,576
  unsigned char* Ww8     = (unsigned char*)(ws + 22020096);    //    262,144
  unsigned short* Vw_bf  = (unsigned short*)(ws + 22282240);   //    524,288
  unsigned short* ht_bf  = (unsigned short*)(ws + 22806528);   // 33,554,432

  float* outLS = (float*)d_out;                    // [8192][104]
  float* outH  = (float*)d_out + (size_t)BB * DD;  // [8192][2048]

  conv_fp8_kernel<<<10240, 256, 0, stream>>>(hidden, Uw, hid8, U8w);
  pad_mixed_kernel<<<6144, 256, 0, stream>>>(line, Ww, Vw, line8, Ww8, Vw_bf);
  gemm1_kernel<<<1024, 512, 0, stream>>>(hid8, line8, U8w, Ww8, Ub, Wb,
                                         outH, ht_bf);
  gemm2_kernel<<<128, 256, 0, stream>>>(ht_bf, Vw_bf, Vb, outLS);
}

// Round 15
// 117.957 us; speedup vs baseline: 6.4355x; 1.1889x over previous
//
#include <hip/hip_runtime.h>
#include <cstdint>
#include <cstddef>

// ---------------------------------------------------------------------------
// RNN_No_FFNN: h_t = sigmoid(hidden@U_w.T + U_b + line@W_w.T + W_b)
//              pred = h_t@V_w.T + V_b ; out0 = segmented log_softmax(pred)
// B=8192, H=2048, D=104.  Outputs: [pred_logsoft (8192*104) | h_t (8192*2048)] f32.
// R15 = R8 FULL SOURCE VERBATIM (best measured total: 117.9us).
//   Purpose: A/A test vs the R8-era measurement + A/B vs R14 isolated to
//   gemm1 (256thr/k-pair-major vs 512thr/plane). If ~118 reproduces, the
//   512-thr gemm1 carries hidden in-stream cost; if ~140, environment drifted
//   between eras and R14 stands.
// gemm1 (R8): MX-fp8 e4m3 (unit scales) mfma_scale_f32_32x32x64_f8f6f4.
//   128x128 tile, 256 thr (2x2 waves, 64x64/wave), BK=128, 2x32KB LDS dbuf
//   -> 64KB -> 2 blocks/CU. k-pair-major LDS layout [pair:4][row:128][32B].
//   Counted vmcnt(8) depth-1 prefetch.
// gemm2: bf16 16x16x32 + fused segmented log-softmax.
// ---------------------------------------------------------------------------

typedef __bf16 bf16x8 __attribute__((ext_vector_type(8)));
typedef float  f32x4  __attribute__((ext_vector_type(4)));
typedef float  f32x16 __attribute__((ext_vector_type(16)));
typedef int    i32x4  __attribute__((ext_vector_type(4)));
typedef int    i32x8  __attribute__((ext_vector_type(8)));
typedef unsigned short ushort8 __attribute__((ext_vector_type(8)));
typedef unsigned char  uchar8  __attribute__((ext_vector_type(8)));
typedef float  float4v __attribute__((ext_vector_type(4)));

#define BB 8192
#define HH 2048
#define DD 104

static __device__ __forceinline__ unsigned short f2bf(float f) {
  unsigned u = __float_as_uint(f);
  unsigned r = (u + 0x7FFFu + ((u >> 16) & 1u)) >> 16;  // RNE
  return (unsigned short)r;
}

// f32 -> OCP e4m3fn, RNE, saturate to 448. Subnormal grid 2^-9 via float2int_rn.
static __device__ __forceinline__ unsigned char f2fp8(float x) {
  unsigned u = __float_as_uint(x);
  unsigned s = (u >> 24) & 0x80u;
  float ax = fabsf(x);
  ax = fminf(ax, 448.0f);
  unsigned code;
  if (ax >= 0.015625f) {                    // normal: exp >= -6
    unsigned b = __float_as_uint(ax);
    unsigned lsb = (b >> 20) & 1u;
    b += 0x0007FFFFu + lsb;                 // RNE at mantissa bit 20
    unsigned e = (b >> 23) & 0xFFu;         // 121..135 after clamp
    code = ((e - 120u) << 3) | ((b >> 20) & 7u);
  } else {                                  // subnormal: step 2^-9 (carry into normal ok)
    code = (unsigned)__float2int_rn(ax * 512.0f);
  }
  return (unsigned char)(s | code);
}

// async global->LDS, 16B per lane (dest = wave-uniform base + lane*16: linear)
#define GLD_LDS(g, l)                                                          \
  __builtin_amdgcn_global_load_lds(                                            \
      (__attribute__((address_space(1))) void*)(g),                            \
      (__attribute__((address_space(3))) void*)(l), 16, 0, 0)

#define MEMFENCE asm volatile("" ::: "memory")
#define MFMA16(a, b, c) __builtin_amdgcn_mfma_f32_16x16x32_bf16((a), (b), (c), 0, 0, 0)

// ---------------------------------------------------------------------------
// Conversion kernels
// ---------------------------------------------------------------------------
__global__ __launch_bounds__(256) void conv_fp8_kernel(
    const float* __restrict__ hidden, const float* __restrict__ Uw,
    unsigned char* __restrict__ out_h, unsigned char* __restrict__ out_u) {
  long long i = ((long long)blockIdx.x * blockDim.x + threadIdx.x) * 8;
  const float* src; unsigned char* dst; long long off;
  if (i < (long long)BB * HH) { src = hidden; dst = out_h; off = i; }
  else { src = Uw; dst = out_u; off = i - (long long)BB * HH; }
  float4v a = *(const float4v*)(src + off);
  float4v b = *(const float4v*)(src + off + 4);
  uchar8 o;
  o[0]=f2fp8(a[0]); o[1]=f2fp8(a[1]); o[2]=f2fp8(a[2]); o[3]=f2fp8(a[3]);
  o[4]=f2fp8(b[0]); o[5]=f2fp8(b[1]); o[6]=f2fp8(b[2]); o[7]=f2fp8(b[3]);
  *(uchar8*)(dst + off) = o;
}

__global__ __launch_bounds__(256) void pad_mixed_kernel(
    const float* __restrict__ line, const float* __restrict__ Ww,
    const float* __restrict__ Vw,
    unsigned char* __restrict__ line8, unsigned char* __restrict__ Ww8,
    unsigned short* __restrict__ Vw_bf) {
  int i = blockIdx.x * blockDim.x + threadIdx.x;
  const int N1 = BB * 128;          // 1048576
  const int N2 = N1 + HH * 128;     // 1310720
  if (i < N1) {
    int r = i >> 7, c = i & 127;
    line8[i] = (c < DD) ? f2fp8(line[r * DD + c]) : (unsigned char)0;
  } else if (i < N2) {
    int j = i - N1; int r = j >> 7, c = j & 127;
    Ww8[j] = (c < DD) ? f2fp8(Ww[r * DD + c]) : (unsigned char)0;
  } else {
    int j = i - N2; int r = j >> 11, c = j & 2047;
    Vw_bf[j] = (r < DD) ? f2bf(Vw[r * 2048 + c]) : (unsigned short)0;
  }
}

// ---------------------------------------------------------------------------
// GEMM1 (R8). LDS: A bufs [0,32768), B bufs [32768,65536); per buf 32KB =
// [pair:4][row:128][32B], pair = 32B k-chunk index within the 128-K tile.
// LDS[pair][row] = G[row][kb + pair*32 .. +32].
// Staging: thread t -> (row = t>>1, half = t&1): source
// G[row][kb + q*32 + half*16], dest = q*4096 + t*16 (linear per wave).
// Fragment read: lane l (lr=l&31, lc=l>>5), k-step s: ONE contiguous 32B at
// (s*2+lc)*4096 + row*32.
// Same k-bijection for A and B -> dot product exact regardless of HW k-order.
// C/D 32x32: n = l&31, m = (reg&3)+8*(reg>>2)+4*(l>>5).
// ---------------------------------------------------------------------------
__global__ __launch_bounds__(256, 2) void gemm1_kernel(
    const unsigned char* __restrict__ A8,   // hidden fp8 [8192][2048]
    const unsigned char* __restrict__ L8,   // line fp8 [8192][128] (zero-pad)
    const unsigned char* __restrict__ U8w,  // U_w fp8 [2048][2048]
    const unsigned char* __restrict__ W8w,  // W_w fp8 [2048][128] (zero-pad)
    const float* __restrict__ Ub, const float* __restrict__ Wb,
    float* __restrict__ outH, unsigned short* __restrict__ outHbf) {
  __shared__ __attribute__((aligned(32))) unsigned char smem[65536];  // 64 KB
  const int t = threadIdx.x;
  const int l = t & 63;
  const int wid = t >> 6;
  const int wr = wid >> 1, wc = wid & 1;    // 2 x 2 waves, 64x64 out each

  // bijective XCD-chunked swizzle: 1024 wgs, 8 XCDs, 128/chunk
  const int bid = blockIdx.x;
  const int wg = (bid & 7) * 128 + (bid >> 3);
  const int brow = (wg >> 4) * 128;   // 64 M tiles
  const int bcol = (wg & 15) * 128;   // 16 N tiles

  const int lr = l & 31;              // fragment row within 32-row band
  const int lc = l >> 5;              // k-half-chunk select

  // staging addressing
  const int sr = t >> 1, sh = (t & 1) * 16;
  const unsigned char* pA = A8 + (size_t)(brow + sr) * 2048 + sh;
  const unsigned char* pL = L8 + (size_t)(brow + sr) * 128 + sh;
  const unsigned char* pU = U8w + (size_t)(bcol + sr) * 2048 + sh;
  const unsigned char* pW = W8w + (size_t)(bcol + sr) * 128 + sh;
  unsigned char* dA = smem + t * 16;            // + buf*16384 + q*4096
  unsigned char* dB = smem + 32768 + t * 16;

  f32x16 acc[2][2] = {};

  auto stage = [&](int kt, int buf) {
    const int kb = kt * 128;
    unsigned char* da = dA + buf * 16384;
    unsigned char* db = dB + buf * 16384;
    if (kb < 2048) {
#pragma unroll
      for (int q = 0; q < 4; ++q) {
        GLD_LDS(pA + kb + q * 32, da + q * 4096);
        GLD_LDS(pU + kb + q * 32, db + q * 4096);
      }
    } else {  // K-tail: line/W_w pads (row stride 128, col base 0)
#pragma unroll
      for (int q = 0; q < 4; ++q) {
        GLD_LDS(pL + q * 32, da + q * 4096);
        GLD_LDS(pW + q * 32, db + q * 4096);
      }
    }
  };

  // prologue: stage K-tile 0 into buf 0
  stage(0, 0);
  asm volatile("s_waitcnt vmcnt(0)" ::: "memory");
  MEMFENCE; __builtin_amdgcn_s_barrier(); MEMFENCE;

  // K = 2176 = 17 tiles of 128 (2048 hidden/U_w + 128 line/W_w concat)
  for (int kt = 0; kt < 17; ++kt) {
    const int cur = kt & 1;
    if (kt < 16) {
      stage(kt + 1, cur ^ 1);
      asm volatile("s_waitcnt vmcnt(8)" ::: "memory");  // tile kt fully landed
    } else {
      asm volatile("s_waitcnt vmcnt(0)" ::: "memory");
    }
    const unsigned char* Ab = smem + cur * 16384;
    const unsigned char* Bb = smem + 32768 + cur * 16384;
#pragma unroll
    for (int s = 0; s < 2; ++s) {           // two K=64 MFMA steps
      const int pr = (s * 2 + lc) * 4096;
      i32x8 af[2], bfv[2];
#pragma unroll
      for (int m = 0; m < 2; ++m)
        af[m] = *(const i32x8*)(Ab + pr + (wr * 64 + m * 32 + lr) * 32);
#pragma unroll
      for (int n = 0; n < 2; ++n)
        bfv[n] = *(const i32x8*)(Bb + pr + (wc * 64 + n * 32 + lr) * 32);
      __builtin_amdgcn_s_setprio(1);
#pragma unroll
      for (int m = 0; m < 2; ++m)
#pragma unroll
        for (int n = 0; n < 2; ++n)
          acc[m][n] = __builtin_amdgcn_mfma_scale_f32_32x32x64_f8f6f4(
              af[m], bfv[n], acc[m][n], 0 /*fp8 A*/, 0 /*fp8 B*/,
              0, 0x7F7F7F7F /*unit scales A*/, 0, 0x7F7F7F7F /*unit scales B*/);
      __builtin_amdgcn_s_setprio(0);
    }
    MEMFENCE; __builtin_amdgcn_s_barrier(); MEMFENCE;  // reads done -> buf reusable
  }

  // epilogue: +bias, sigmoid, dual write.
  // C/D 32x32: n = l&31, m = (reg&3) + 8*(reg>>2) + 4*(l>>5)
#pragma unroll
  for (int nf = 0; nf < 2; ++nf) {
    const int col = bcol + wc * 64 + nf * 32 + lr;
    const float bias = Ub[col] + Wb[col];
#pragma unroll
    for (int mf = 0; mf < 2; ++mf) {
#pragma unroll
      for (int reg = 0; reg < 16; ++reg) {
        const int row = brow + wr * 64 + mf * 32 + (reg & 3) + 8 * (reg >> 2) + 4 * lc;
        const float v = acc[mf][nf][reg] + bias;
        const float h = 1.0f / (1.0f + __expf(-v));
        const size_t idx = (size_t)row * HH + col;
        outH[idx] = h;
        outHbf[idx] = f2bf(h);
      }
    }
  }
}

// ---------------------------------------------------------------------------
// GEMM2 (bf16): pred = h_t@V_w.T + V_b + fused seg log-softmax
// ---------------------------------------------------------------------------
template <int NM, int NN>
static __device__ __forceinline__ void mfma_step(
    const unsigned short* sA, const unsigned short* sB, int arow0, int brow0,
    int frow, int fk, f32x4 (&acc)[NM][NN]) {
  bf16x8 af[NM], bfr[NN];
#pragma unroll
  for (int m = 0; m < NM; ++m)
    af[m] = *(const bf16x8*)(sA + (arow0 + m * 16 + frow) * 32 + fk);
#pragma unroll
  for (int n = 0; n < NN; ++n)
    bfr[n] = *(const bf16x8*)(sB + (brow0 + n * 16 + frow) * 32 + fk);
#pragma unroll
  for (int m = 0; m < NM; ++m)
#pragma unroll
    for (int n = 0; n < NN; ++n)
      acc[m][n] = MFMA16(af[m], bfr[n], acc[m][n]);
}

__global__ __launch_bounds__(256, 2) void gemm2_kernel(
    const unsigned short* __restrict__ A,   // h_t bf16 [8192][2048]
    const unsigned short* __restrict__ Bm,  // Vw_bf [128][2048]
    const float* __restrict__ Vb,
    float* __restrict__ outLS) {            // [8192][104] f32
  __shared__ unsigned short sA[64 * 32];
  __shared__ unsigned short sB[128 * 32];
  __shared__ float pred[64 * 105];
  const int t = threadIdx.x;
  const int l = t & 63;
  const int wid = t >> 6, wr = wid >> 1, wc = wid & 1;
  const int brow = blockIdx.x * 64;
  const int srow = t >> 2, scg = t & 3;
  const int frow = l & 15, fk = (l >> 4) * 8;

  const unsigned short* gA = A + (size_t)(brow + srow) * HH + scg * 8;
  const unsigned short* gB = Bm + (size_t)srow * HH + scg * 8;
  unsigned short* lA = sA + t * 8;
  unsigned short* lB = sB + t * 8;

  f32x4 acc[2][4] = {};
  for (int ks = 0; ks < 64; ++ks) {
    __syncthreads();
    GLD_LDS(gA, lA);
    GLD_LDS(gB, lB);
    GLD_LDS(gB + 64 * HH, lB + 64 * 32);
    gA += 32; gB += 32;
    __syncthreads();
    mfma_step<2, 4>(sA, sB, wr * 32, wc * 64, frow, fk, acc);
  }

#pragma unroll
  for (int n = 0; n < 4; ++n) {
    const int col = wc * 64 + n * 16 + frow;
    if (col < DD) {
      const float vb = Vb[col];
#pragma unroll
      for (int m = 0; m < 2; ++m) {
        const int r0 = wr * 32 + m * 16 + (l >> 4) * 4;
#pragma unroll
        for (int j = 0; j < 4; ++j)
          pred[(r0 + j) * 105 + col] = acc[m][n][j] + vb;
      }
    }
  }
  __syncthreads();

  if (t < 64) {
    const int segb[11] = {0, 13, 26, 39, 48, 52, 65, 78, 91, 100, 104};
    const float* p = pred + t * 105;
    float* o = outLS + (size_t)(brow + t) * DD;
    for (int s = 0; s < 10; ++s) {
      const int a = segb[s], b = segb[s + 1];
      float mx = -3.0e38f;
      for (int c = a; c < b; ++c) mx = fmaxf(mx, p[c]);
      float sum = 0.0f;
      for (int c = a; c < b; ++c) sum += __expf(p[c] - mx);
      const float ls = __logf(sum) + mx;
      for (int c = a; c < b; ++c) o[c] = p[c] - ls;
    }
  }
}

// ---------------------------------------------------------------------------
// Launch
// ---------------------------------------------------------------------------
extern "C" void kernel_launch(void* const* d_in, const int* in_sizes, int n_in,
                              void* d_out, int out_size, void* d_ws, size_t ws_size,
                              hipStream_t stream) {
  (void)in_sizes; (void)n_in; (void)out_size; (void)ws_size;
  const float* line   = (const float*)d_in[0];
  const float* hidden = (const float*)d_in[1];
  const float* Uw     = (const float*)d_in[2];
  const float* Ub     = (const float*)d_in[3];
  const float* Ww     = (const float*)d_in[4];
  const float* Wb     = (const float*)d_in[5];
  const float* Vw     = (const float*)d_in[6];
  const float* Vb     = (const float*)d_in[7];

  char* ws = (char*)d_ws;
  unsigned char* hid8    = (unsigned char*)(ws);               // 16,777,216
  unsigned char* U8w     = (unsigned char*)(ws + 16777216);    //  4,194,304
  unsigned char* line8   = (unsigned char*)(ws + 20971520);    //  1,048,576
  unsigned char* Ww8     = (unsigned char*)(ws + 22020096);    //    262,144
  unsigned short* Vw_bf  = (unsigned short*)(ws + 22282240);   //    524,288
  unsigned short* ht_bf  = (unsigned short*)(ws + 22806528);   // 33,554,432

  float* outLS = (float*)d_out;                    // [8192][104]
  float* outH  = (float*)d_out + (size_t)BB * DD;  // [8192][2048]

  conv_fp8_kernel<<<10240, 256, 0, stream>>>(hidden, Uw, hid8, U8w);
  pad_mixed_kernel<<<6144, 256, 0, stream>>>(line, Ww, Vw, line8, Ww8, Vw_bf);
  gemm1_kernel<<<1024, 256, 0, stream>>>(hid8, line8, U8w, Ww8, Ub, Wb,
                                         outH, ht_bf);
  gemm2_kernel<<<128, 256, 0, stream>>>(ht_bf, Vw_bf, Vb, outLS);
}

// Round 16
// 117.727 us; speedup vs baseline: 6.4480x; 1.0020x over previous
//
#include <hip/hip_runtime.h>
#include <cstdint>
#include <cstddef>

// ---------------------------------------------------------------------------
// RNN_No_FFNN: h_t = sigmoid(hidden@U_w.T + U_b + line@W_w.T + W_b)
//              pred = h_t@V_w.T + V_b ; out0 = segmented log_softmax(pred)
// B=8192, H=2048, D=104.  Outputs: [pred_logsoft (8192*104) | h_t (8192*2048)] f32.
// R16 = R15/R8 config (best, 117.9us x2 reproduced) with conv+pad merged
//   into ONE prep_kernel launch (saves one dispatch + gap; pad blocks fill
//   conv tail).  gemm1/gemm2 byte-identical to R15.
// gemm1: MX-fp8 e4m3 (unit scales) mfma_scale_f32_32x32x64_f8f6f4.
//   128x128 tile, 256 thr (2x2 waves, 64x64/wave), BK=128, 2x32KB LDS dbuf,
//   k-pair-major LDS layout [pair:4][row:128][32B], counted vmcnt(8).
// gemm2: bf16 16x16x32 + fused segmented log-softmax (64-row/128-block).
// ---------------------------------------------------------------------------

typedef __bf16 bf16x8 __attribute__((ext_vector_type(8)));
typedef float  f32x4  __attribute__((ext_vector_type(4)));
typedef float  f32x16 __attribute__((ext_vector_type(16)));
typedef int    i32x4  __attribute__((ext_vector_type(4)));
typedef int    i32x8  __attribute__((ext_vector_type(8)));
typedef unsigned short ushort8 __attribute__((ext_vector_type(8)));
typedef unsigned char  uchar8  __attribute__((ext_vector_type(8)));
typedef float  float4v __attribute__((ext_vector_type(4)));

#define BB 8192
#define HH 2048
#define DD 104

static __device__ __forceinline__ unsigned short f2bf(float f) {
  unsigned u = __float_as_uint(f);
  unsigned r = (u + 0x7FFFu + ((u >> 16) & 1u)) >> 16;  // RNE
  return (unsigned short)r;
}

// f32 -> OCP e4m3fn, RNE, saturate to 448. Subnormal grid 2^-9 via float2int_rn.
static __device__ __forceinline__ unsigned char f2fp8(float x) {
  unsigned u = __float_as_uint(x);
  unsigned s = (u >> 24) & 0x80u;
  float ax = fabsf(x);
  ax = fminf(ax, 448.0f);
  unsigned code;
  if (ax >= 0.015625f) {                    // normal: exp >= -6
    unsigned b = __float_as_uint(ax);
    unsigned lsb = (b >> 20) & 1u;
    b += 0x0007FFFFu + lsb;                 // RNE at mantissa bit 20
    unsigned e = (b >> 23) & 0xFFu;         // 121..135 after clamp
    code = ((e - 120u) << 3) | ((b >> 20) & 7u);
  } else {                                  // subnormal: step 2^-9 (carry into normal ok)
    code = (unsigned)__float2int_rn(ax * 512.0f);
  }
  return (unsigned char)(s | code);
}

// async global->LDS, 16B per lane (dest = wave-uniform base + lane*16: linear)
#define GLD_LDS(g, l)                                                          \
  __builtin_amdgcn_global_load_lds(                                            \
      (__attribute__((address_space(1))) void*)(g),                            \
      (__attribute__((address_space(3))) void*)(l), 16, 0, 0)

#define MEMFENCE asm volatile("" ::: "memory")
#define MFMA16(a, b, c) __builtin_amdgcn_mfma_f32_16x16x32_bf16((a), (b), (c), 0, 0, 0)

// ---------------------------------------------------------------------------
// prep_kernel = conv_fp8 (blocks 0..10239) + pad_mixed (blocks 10240..16383)
// merged; bodies byte-identical to R15's two kernels.
// ---------------------------------------------------------------------------
__global__ __launch_bounds__(256) void prep_kernel(
    const float* __restrict__ hidden, const float* __restrict__ Uw,
    const float* __restrict__ line, const float* __restrict__ Ww,
    const float* __restrict__ Vw,
    unsigned char* __restrict__ out_h, unsigned char* __restrict__ out_u,
    unsigned char* __restrict__ line8, unsigned char* __restrict__ Ww8,
    unsigned short* __restrict__ Vw_bf) {
  const int bid = blockIdx.x;
  if (bid < 10240) {
    // conv part: hidden (16777216) then U_w (4194304), f32 -> fp8, 8/thread
    long long i = ((long long)bid * blockDim.x + threadIdx.x) * 8;
    const float* src; unsigned char* dst; long long off;
    if (i < (long long)BB * HH) { src = hidden; dst = out_h; off = i; }
    else { src = Uw; dst = out_u; off = i - (long long)BB * HH; }
    float4v a = *(const float4v*)(src + off);
    float4v b = *(const float4v*)(src + off + 4);
    uchar8 o;
    o[0]=f2fp8(a[0]); o[1]=f2fp8(a[1]); o[2]=f2fp8(a[2]); o[3]=f2fp8(a[3]);
    o[4]=f2fp8(b[0]); o[5]=f2fp8(b[1]); o[6]=f2fp8(b[2]); o[7]=f2fp8(b[3]);
    *(uchar8*)(dst + off) = o;
  } else {
    // pad part: line->line8[8192,128], Ww->Ww8[2048,128], Vw->Vw_bf[128,2048]
    int i = (bid - 10240) * blockDim.x + threadIdx.x;
    const int N1 = BB * 128;          // 1048576
    const int N2 = N1 + HH * 128;     // 1310720
    if (i < N1) {
      int r = i >> 7, c = i & 127;
      line8[i] = (c < DD) ? f2fp8(line[r * DD + c]) : (unsigned char)0;
    } else if (i < N2) {
      int j = i - N1; int r = j >> 7, c = j & 127;
      Ww8[j] = (c < DD) ? f2fp8(Ww[r * DD + c]) : (unsigned char)0;
    } else {
      int j = i - N2; int r = j >> 11, c = j & 2047;
      Vw_bf[j] = (r < DD) ? f2bf(Vw[r * 2048 + c]) : (unsigned short)0;
    }
  }
}

// ---------------------------------------------------------------------------
// GEMM1 (R8/R15 exact). LDS: A bufs [0,32768), B bufs [32768,65536); per buf
// 32KB = [pair:4][row:128][32B], pair = 32B k-chunk of the 128-K tile.
// LDS[pair][row] = G[row][kb + pair*32 .. +32].
// Staging: thread t -> (row = t>>1, half = t&1): source
// G[row][kb + q*32 + half*16], dest = q*4096 + t*16 (linear per wave).
// Fragment read: lane l (lr=l&31, lc=l>>5), k-step s: ONE contiguous 32B at
// (s*2+lc)*4096 + row*32.
// Same k-bijection for A and B -> dot product exact regardless of HW k-order.
// C/D 32x32: n = l&31, m = (reg&3)+8*(reg>>2)+4*(l>>5).
// ---------------------------------------------------------------------------
__global__ __launch_bounds__(256, 2) void gemm1_kernel(
    const unsigned char* __restrict__ A8,   // hidden fp8 [8192][2048]
    const unsigned char* __restrict__ L8,   // line fp8 [8192][128] (zero-pad)
    const unsigned char* __restrict__ U8w,  // U_w fp8 [2048][2048]
    const unsigned char* __restrict__ W8w,  // W_w fp8 [2048][128] (zero-pad)
    const float* __restrict__ Ub, const float* __restrict__ Wb,
    float* __restrict__ outH, unsigned short* __restrict__ outHbf) {
  __shared__ __attribute__((aligned(32))) unsigned char smem[65536];  // 64 KB
  const int t = threadIdx.x;
  const int l = t & 63;
  const int wid = t >> 6;
  const int wr = wid >> 1, wc = wid & 1;    // 2 x 2 waves, 64x64 out each

  // bijective XCD-chunked swizzle: 1024 wgs, 8 XCDs, 128/chunk
  const int bid = blockIdx.x;
  const int wg = (bid & 7) * 128 + (bid >> 3);
  const int brow = (wg >> 4) * 128;   // 64 M tiles
  const int bcol = (wg & 15) * 128;   // 16 N tiles

  const int lr = l & 31;              // fragment row within 32-row band
  const int lc = l >> 5;              // k-half-chunk select

  // staging addressing
  const int sr = t >> 1, sh = (t & 1) * 16;
  const unsigned char* pA = A8 + (size_t)(brow + sr) * 2048 + sh;
  const unsigned char* pL = L8 + (size_t)(brow + sr) * 128 + sh;
  const unsigned char* pU = U8w + (size_t)(bcol + sr) * 2048 + sh;
  const unsigned char* pW = W8w + (size_t)(bcol + sr) * 128 + sh;
  unsigned char* dA = smem + t * 16;            // + buf*16384 + q*4096
  unsigned char* dB = smem + 32768 + t * 16;

  f32x16 acc[2][2] = {};

  auto stage = [&](int kt, int buf) {
    const int kb = kt * 128;
    unsigned char* da = dA + buf * 16384;
    unsigned char* db = dB + buf * 16384;
    if (kb < 2048) {
#pragma unroll
      for (int q = 0; q < 4; ++q) {
        GLD_LDS(pA + kb + q * 32, da + q * 4096);
        GLD_LDS(pU + kb + q * 32, db + q * 4096);
      }
    } else {  // K-tail: line/W_w pads (row stride 128, col base 0)
#pragma unroll
      for (int q = 0; q < 4; ++q) {
        GLD_LDS(pL + q * 32, da + q * 4096);
        GLD_LDS(pW + q * 32, db + q * 4096);
      }
    }
  };

  // prologue: stage K-tile 0 into buf 0
  stage(0, 0);
  asm volatile("s_waitcnt vmcnt(0)" ::: "memory");
  MEMFENCE; __builtin_amdgcn_s_barrier(); MEMFENCE;

  // K = 2176 = 17 tiles of 128 (2048 hidden/U_w + 128 line/W_w concat)
  for (int kt = 0; kt < 17; ++kt) {
    const int cur = kt & 1;
    if (kt < 16) {
      stage(kt + 1, cur ^ 1);
      asm volatile("s_waitcnt vmcnt(8)" ::: "memory");  // tile kt fully landed
    } else {
      asm volatile("s_waitcnt vmcnt(0)" ::: "memory");
    }
    const unsigned char* Ab = smem + cur * 16384;
    const unsigned char* Bb = smem + 32768 + cur * 16384;
#pragma unroll
    for (int s = 0; s < 2; ++s) {           // two K=64 MFMA steps
      const int pr = (s * 2 + lc) * 4096;
      i32x8 af[2], bfv[2];
#pragma unroll
      for (int m = 0; m < 2; ++m)
        af[m] = *(const i32x8*)(Ab + pr + (wr * 64 + m * 32 + lr) * 32);
#pragma unroll
      for (int n = 0; n < 2; ++n)
        bfv[n] = *(const i32x8*)(Bb + pr + (wc * 64 + n * 32 + lr) * 32);
      __builtin_amdgcn_s_setprio(1);
#pragma unroll
      for (int m = 0; m < 2; ++m)
#pragma unroll
        for (int n = 0; n < 2; ++n)
          acc[m][n] = __builtin_amdgcn_mfma_scale_f32_32x32x64_f8f6f4(
              af[m], bfv[n], acc[m][n], 0 /*fp8 A*/, 0 /*fp8 B*/,
              0, 0x7F7F7F7F /*unit scales A*/, 0, 0x7F7F7F7F /*unit scales B*/);
      __builtin_amdgcn_s_setprio(0);
    }
    MEMFENCE; __builtin_amdgcn_s_barrier(); MEMFENCE;  // reads done -> buf reusable
  }

  // epilogue: +bias, sigmoid, dual write.
  // C/D 32x32: n = l&31, m = (reg&3) + 8*(reg>>2) + 4*(l>>5)
#pragma unroll
  for (int nf = 0; nf < 2; ++nf) {
    const int col = bcol + wc * 64 + nf * 32 + lr;
    const float bias = Ub[col] + Wb[col];
#pragma unroll
    for (int mf = 0; mf < 2; ++mf) {
#pragma unroll
      for (int reg = 0; reg < 16; ++reg) {
        const int row = brow + wr * 64 + mf * 32 + (reg & 3) + 8 * (reg >> 2) + 4 * lc;
        const float v = acc[mf][nf][reg] + bias;
        const float h = 1.0f / (1.0f + __expf(-v));
        const size_t idx = (size_t)row * HH + col;
        outH[idx] = h;
        outHbf[idx] = f2bf(h);
      }
    }
  }
}

// ---------------------------------------------------------------------------
// GEMM2 (R8/R15 exact, bf16): pred = h_t@V_w.T + V_b + fused seg log-softmax
// ---------------------------------------------------------------------------
template <int NM, int NN>
static __device__ __forceinline__ void mfma_step(
    const unsigned short* sA, const unsigned short* sB, int arow0, int brow0,
    int frow, int fk, f32x4 (&acc)[NM][NN]) {
  bf16x8 af[NM], bfr[NN];
#pragma unroll
  for (int m = 0; m < NM; ++m)
    af[m] = *(const bf16x8*)(sA + (arow0 + m * 16 + frow) * 32 + fk);
#pragma unroll
  for (int n = 0; n < NN; ++n)
    bfr[n] = *(const bf16x8*)(sB + (brow0 + n * 16 + frow) * 32 + fk);
#pragma unroll
  for (int m = 0; m < NM; ++m)
#pragma unroll
    for (int n = 0; n < NN; ++n)
      acc[m][n] = MFMA16(af[m], bfr[n], acc[m][n]);
}

__global__ __launch_bounds__(256, 2) void gemm2_kernel(
    const unsigned short* __restrict__ A,   // h_t bf16 [8192][2048]
    const unsigned short* __restrict__ Bm,  // Vw_bf [128][2048]
    const float* __restrict__ Vb,
    float* __restrict__ outLS) {            // [8192][104] f32
  __shared__ unsigned short sA[64 * 32];
  __shared__ unsigned short sB[128 * 32];
  __shared__ float pred[64 * 105];
  const int t = threadIdx.x;
  const int l = t & 63;
  const int wid = t >> 6, wr = wid >> 1, wc = wid & 1;
  const int brow = blockIdx.x * 64;
  const int srow = t >> 2, scg = t & 3;
  const int frow = l & 15, fk = (l >> 4) * 8;

  const unsigned short* gA = A + (size_t)(brow + srow) * HH + scg * 8;
  const unsigned short* gB = Bm + (size_t)srow * HH + scg * 8;
  unsigned short* lA = sA + t * 8;
  unsigned short* lB = sB + t * 8;

  f32x4 acc[2][4] = {};
  for (int ks = 0; ks < 64; ++ks) {
    __syncthreads();
    GLD_LDS(gA, lA);
    GLD_LDS(gB, lB);
    GLD_LDS(gB + 64 * HH, lB + 64 * 32);
    gA += 32; gB += 32;
    __syncthreads();
    mfma_step<2, 4>(sA, sB, wr * 32, wc * 64, frow, fk, acc);
  }

#pragma unroll
  for (int n = 0; n < 4; ++n) {
    const int col = wc * 64 + n * 16 + frow;
    if (col < DD) {
      const float vb = Vb[col];
#pragma unroll
      for (int m = 0; m < 2; ++m) {
        const int r0 = wr * 32 + m * 16 + (l >> 4) * 4;
#pragma unroll
        for (int j = 0; j < 4; ++j)
          pred[(r0 + j) * 105 + col] = acc[m][n][j] + vb;
      }
    }
  }
  __syncthreads();

  if (t < 64) {
    const int segb[11] = {0, 13, 26, 39, 48, 52, 65, 78, 91, 100, 104};
    const float* p = pred + t * 105;
    float* o = outLS + (size_t)(brow + t) * DD;
    for (int s = 0; s < 10; ++s) {
      const int a = segb[s], b = segb[s + 1];
      float mx = -3.0e38f;
      for (int c = a; c < b; ++c) mx = fmaxf(mx, p[c]);
      float sum = 0.0f;
      for (int c = a; c < b; ++c) sum += __expf(p[c] - mx);
      const float ls = __logf(sum) + mx;
      for (int c = a; c < b; ++c) o[c] = p[c] - ls;
    }
  }
}

// ---------------------------------------------------------------------------
// Launch
// ---------------------------------------------------------------------------
extern "C" void kernel_launch(void* const* d_in, const int* in_sizes, int n_in,
                              void* d_out, int out_size, void* d_ws, size_t ws_size,
                              hipStream_t stream) {
  (void)in_sizes; (void)n_in; (void)out_size; (void)ws_size;
  const float* line   = (const float*)d_in[0];
  const float* hidden = (const float*)d_in[1];
  const float* Uw     = (const float*)d_in[2];
  const float* Ub     = (const float*)d_in[3];
  const float* Ww     = (const float*)d_in[4];
  const float* Wb     = (const float*)d_in[5];
  const float* Vw     = (const float*)d_in[6];
  const float* Vb     = (const float*)d_in[7];

  char* ws = (char*)d_ws;
  unsigned char* hid8    = (unsigned char*)(ws);               // 16,777,216
  unsigned char* U8w     = (unsigned char*)(ws + 16777216);    //  4,194,304
  unsigned char* line8   = (unsigned char*)(ws + 20971520);    //  1,048,576
  unsigned char* Ww8     = (unsigned char*)(ws + 22020096);    //    262,144
  unsigned short* Vw_bf  = (unsigned short*)(ws + 22282240);   //    524,288
  unsigned short* ht_bf  = (unsigned short*)(ws + 22806528);   // 33,554,432

  float* outLS = (float*)d_out;                    // [8192][104]
  float* outH  = (float*)d_out + (size_t)BB * DD;  // [8192][2048]

  // merged conv (10240 blocks) + pad (6144 blocks)
  prep_kernel<<<16384, 256, 0, stream>>>(hidden, Uw, line, Ww, Vw,
                                         hid8, U8w, line8, Ww8, Vw_bf);
  gemm1_kernel<<<1024, 256, 0, stream>>>(hid8, line8, U8w, Ww8, Ub, Wb,
                                         outH, ht_bf);
  gemm2_kernel<<<128, 256, 0, stream>>>(ht_bf, Vw_bf, Vb, outLS);
}